// Round 9
// baseline (41.017 us; speedup 1.0000x reference)
//
#include <hip/hip_runtime.h>
#include <hip/hip_bf16.h>

// Problem constants (from reference setup_inputs):
//   x: [B=4, NC=2000, F=4, H=64] fp32          (8.2 MB; 2 MB per batch slice)
//   fine_to_coarse: [NF=50000] int32 in [0,NC) (200 KB)
//   out: [B=4, NF=50000, F=4, H=64] fp32       (204.8 MB — write-BW bound)
// Row per (b,node) = F*H = 256 floats = 1 KB = 64 float4 = one wave.
//
// R8 (best: 37.4 us = 1 row/wave, TPB=1024, XCD-chunk swizzle, NT stores)
// with ONE change: plain cached stores instead of nontemporal. Theory: with
// the swizzle confining each XCD's read set to ~2 MB of re-referenced lines,
// write-allocate no longer evicts x, and L2-buffered writes drain to HBM in
// more efficient full-line bursts (the 6.9 TB/s fill kernel uses plain
// stores). A/B vs R8.

#define B_     4
#define NC_    2000
#define NF_    50000
#define ROW_F4 64
#define TPB    1024          // 16 waves/block = 16 rows/block
#define BPB    3125          // blocks per batch: 50000/16
#define NWG    (BPB * B_)    // 12500 total workgroups
#define NXCD   8

typedef float vf4 __attribute__((ext_vector_type(4)));

__global__ __launch_bounds__(TPB) void unpool_gather_kernel(
    const vf4* __restrict__ x,      // [B, NC, 64] vf4
    const int* __restrict__ ftc,    // [NF]
    vf4*       __restrict__ out)    // [B, NF, 64] vf4
{
    // Bijective XCD swizzle (m204): nwg=12500 -> q=1562, r=4.
    const int orig = blockIdx.x;
    const int xcd  = orig & (NXCD - 1);
    const int j    = orig >> 3;
    const int q    = NWG / NXCD;        // 1562
    const int r    = NWG % NXCD;        // 4
    const int swz  = (xcd < r ? xcd * (q + 1)
                              : r * (q + 1) + (xcd - r) * q) + j;

    const int b   = swz / BPB;
    const int blk = swz % BPB;

    const int widx = threadIdx.x >> 6;  // wave in block: 0..15
    const int lane = threadIdx.x & 63;
    const int nf   = blk * 16 + widx;   // one nf row per wave

    const int c = ftc[nf];              // wave-broadcast load

    const vf4 v = x[((size_t)b * NC_ + c) * ROW_F4 + lane];
    out[((size_t)b * NF_ + nf) * ROW_F4 + lane] = v;
}

extern "C" void kernel_launch(void* const* d_in, const int* in_sizes, int n_in,
                              void* d_out, int out_size, void* d_ws, size_t ws_size,
                              hipStream_t stream) {
    const vf4* x   = (const vf4*)d_in[0];
    const int* ftc = (const int*)d_in[1];
    vf4*       out = (vf4*)d_out;

    dim3 grid(NWG);
    dim3 block(TPB);
    unpool_gather_kernel<<<grid, block, 0, stream>>>(x, ftc, out);
}

// Round 10
// 39.217 us; speedup vs baseline: 1.0459x; 1.0459x over previous
//
#include <hip/hip_runtime.h>
#include <hip/hip_bf16.h>

// Problem constants (from reference setup_inputs):
//   x: [B=4, NC=2000, F=4, H=64] fp32          (8.2 MB; 2 MB per batch slice)
//   fine_to_coarse: [NF=50000] int32 in [0,NC) (200 KB)
//   out: [B=4, NF=50000, F=4, H=64] fp32       (204.8 MB — write-BW bound)
// Row per (b,node) = F*H = 256 floats = 1 KB = 64 float4.
//
// Best = R8: 37.4 us (1 row/wave, XCD-chunk swizzle, NT stores).
// This round, ONE change: 2 rows per wave (int2 idx broadcast, 2 independent
// x-load->NT-store chains, 2 KB contiguous writes/wave). TPB=512 keeps
// 16 rows/block so NWG=12500 and the m204 bijective swizzle are unchanged.

#define B_     4
#define NC_    2000
#define NF_    50000
#define ROW_F4 64
#define TPB    512           // 8 waves/block x 2 rows = 16 rows/block
#define BPB    3125          // blocks per batch: 50000/16
#define NWG    (BPB * B_)    // 12500 total workgroups
#define NXCD   8

typedef float vf4 __attribute__((ext_vector_type(4)));
typedef int   vi2 __attribute__((ext_vector_type(2)));

__global__ __launch_bounds__(TPB) void unpool_gather_kernel(
    const vf4* __restrict__ x,      // [B, NC, 64] vf4
    const int* __restrict__ ftc,    // [NF]
    vf4*       __restrict__ out)    // [B, NF, 64] vf4
{
    // Bijective XCD swizzle (m204): nwg=12500 -> q=1562, r=4.
    const int orig = blockIdx.x;
    const int xcd  = orig & (NXCD - 1);
    const int j    = orig >> 3;
    const int q    = NWG / NXCD;        // 1562
    const int r    = NWG % NXCD;        // 4
    const int swz  = (xcd < r ? xcd * (q + 1)
                              : r * (q + 1) + (xcd - r) * q) + j;

    const int b   = swz / BPB;
    const int blk = swz % BPB;

    const int widx = threadIdx.x >> 6;  // wave in block: 0..7
    const int lane = threadIdx.x & 63;
    const int nf0  = blk * 16 + widx * 2;   // 2 consecutive rows per wave

    // One 8B broadcast load fetches both indices.
    const vi2 c2 = *(const vi2*)&ftc[nf0];

    const vf4* __restrict__ xb = x + (size_t)b * NC_ * ROW_F4 + lane;
    vf4* __restrict__ ob = out + ((size_t)b * NF_ + nf0) * ROW_F4 + lane;

    const vf4 v0 = xb[(size_t)c2.x * ROW_F4];
    const vf4 v1 = xb[(size_t)c2.y * ROW_F4];

    __builtin_nontemporal_store(v0, &ob[0 * ROW_F4]);
    __builtin_nontemporal_store(v1, &ob[1 * ROW_F4]);
}

extern "C" void kernel_launch(void* const* d_in, const int* in_sizes, int n_in,
                              void* d_out, int out_size, void* d_ws, size_t ws_size,
                              hipStream_t stream) {
    const vf4* x   = (const vf4*)d_in[0];
    const int* ftc = (const int*)d_in[1];
    vf4*       out = (vf4*)d_out;

    dim3 grid(NWG);
    dim3 block(TPB);
    unpool_gather_kernel<<<grid, block, 0, stream>>>(x, ftc, out);
}

// Round 11
// 37.349 us; speedup vs baseline: 1.0982x; 1.0500x over previous
//
#include <hip/hip_runtime.h>
#include <hip/hip_bf16.h>

// Problem constants (from reference setup_inputs):
//   x: [B=4, NC=2000, F=4, H=64] fp32          (8.2 MB; 2 MB per batch slice)
//   fine_to_coarse: [NF=50000] int32 in [0,NC) (200 KB)
//   out: [B=4, NF=50000, F=4, H=64] fp32       (204.8 MB — write-BW bound)
// Row per (b,node) = F*H = 256 floats = 1 KB = 64 float4 = one wave.
//
// Best = R8: 37.4 us (1 row/wave, TPB=1024, m204 XCD-chunk swizzle, NT
// stores). Falsified since: WG-count (R5 null), multi-row/wave (R7/R10
// regress), plain stores (R9 regress). This round, ONE change: force the
// index fetch onto the SCALAR path (readfirstlane -> s_load through the
// constant cache) — removes one VMEM hop from the wave's dependent chain.
// Prediction: null-to-small; null => declare roofline.

#define B_     4
#define NC_    2000
#define NF_    50000
#define ROW_F4 64
#define TPB    1024          // 16 waves/block = 16 rows/block
#define BPB    3125          // blocks per batch: 50000/16
#define NWG    (BPB * B_)    // 12500 total workgroups
#define NXCD   8

typedef float vf4 __attribute__((ext_vector_type(4)));

__global__ __launch_bounds__(TPB) void unpool_gather_kernel(
    const vf4* __restrict__ x,      // [B, NC, 64] vf4
    const int* __restrict__ ftc,    // [NF]
    vf4*       __restrict__ out)    // [B, NF, 64] vf4
{
    // Bijective XCD swizzle (m204): nwg=12500 -> q=1562, r=4.
    const int orig = blockIdx.x;
    const int xcd  = orig & (NXCD - 1);
    const int j    = orig >> 3;
    const int q    = NWG / NXCD;        // 1562
    const int r    = NWG % NXCD;        // 4
    const int swz  = (xcd < r ? xcd * (q + 1)
                              : r * (q + 1) + (xcd - r) * q) + j;

    const int b   = swz / BPB;
    const int blk = swz % BPB;

    const int widx = threadIdx.x >> 6;  // wave in block: 0..15
    const int lane = threadIdx.x & 63;

    // nf is wave-uniform; readfirstlane pins it to an SGPR so the index
    // fetch becomes an s_load (scalar cache), off the VMEM critical path.
    const int nf = __builtin_amdgcn_readfirstlane(blk * 16 + widx);
    const int c  = ftc[nf];

    const vf4 v = x[((size_t)b * NC_ + c) * ROW_F4 + lane];
    __builtin_nontemporal_store(v, &out[((size_t)b * NF_ + nf) * ROW_F4 + lane]);
}

extern "C" void kernel_launch(void* const* d_in, const int* in_sizes, int n_in,
                              void* d_out, int out_size, void* d_ws, size_t ws_size,
                              hipStream_t stream) {
    const vf4* x   = (const vf4*)d_in[0];
    const int* ftc = (const int*)d_in[1];
    vf4*       out = (vf4*)d_out;

    dim3 grid(NWG);
    dim3 block(TPB);
    unpool_gather_kernel<<<grid, block, 0, stream>>>(x, ftc, out);
}